// Round 12
// baseline (46.856 us; speedup 1.0000x reference)
//
#include <hip/hip_runtime.h>
#include <hip/hip_bf16.h>
#include <climits>

typedef __bf16 bf16;
typedef __bf16 bf16x4 __attribute__((ext_vector_type(4)));
typedef __bf16 bf16x8 __attribute__((ext_vector_type(8)));
typedef float f32x4 __attribute__((ext_vector_type(4)));

#define NB 8
#define L_ 4096
#define C_ 512
#define KW 5
#define NS 8
#define BM 32

// ---------------------------------------------------------------------------
// bias2[n] = b_pw[n] + sum_c b_dw[c]*w_pw[n][c]   (fp32-exact)
// ---------------------------------------------------------------------------
__global__ __launch_bounds__(256) void bias_kernel(
    const float* __restrict__ w_pw, const float* __restrict__ b_dw,
    const float* __restrict__ b_pw, float* __restrict__ bias2) {
  const int n = blockIdx.x;
  const int t = threadIdx.x;
  float2 v = *(const float2*)(w_pw + n * C_ + 2 * t);
  float2 bb = *(const float2*)(b_dw + 2 * t);
  float s = v.x * bb.x + v.y * bb.y;
#pragma unroll
  for (int off = 32; off; off >>= 1) s += __shfl_down(s, off, 64);
  __shared__ float part[4];
  if ((t & 63) == 0) part[t >> 6] = s;
  __syncthreads();
  if (t == 0) bias2[n] = b_pw[n] + part[0] + part[1] + part[2] + part[3];
}

// ---------------------------------------------------------------------------
// pack: w_pw fp32 -> bf16 in MFMA B-fragment order (8 groups x 4 frags).
// gid = ((kk*8 + g)*4 + nf)*64 + lane holds 8 bf16 (16B):
//   col n = g*64 + nf*16 + (lane&15), ch c = kk*32 + (lane>>4)*8 .. +8
// A wave owning 128 cols (wn) reads groups 2wn,2wn+1 = 8 contiguous frags.
// ---------------------------------------------------------------------------
__global__ __launch_bounds__(256) void pack_kernel(const float* __restrict__ w_pw,
                                                   bf16* __restrict__ pk) {
  const int gid = blockIdx.x * 256 + threadIdx.x;  // 0..32767
  const int lane = gid & 63;
  const int nf = (gid >> 6) & 3;
  const int g = (gid >> 8) & 7;
  const int kk = gid >> 11;
  const int n = g * 64 + nf * 16 + (lane & 15);
  const int c = kk * 32 + (lane >> 4) * 8;
  const float* s = w_pw + n * C_ + c;
  float4 a = *(const float4*)s;
  float4 b4 = *(const float4*)(s + 4);
  bf16x8 h;
  h[0] = (bf16)a.x; h[1] = (bf16)a.y; h[2] = (bf16)a.z; h[3] = (bf16)a.w;
  h[4] = (bf16)b4.x; h[5] = (bf16)b4.y; h[6] = (bf16)b4.z; h[7] = (bf16)b4.w;
  *(bf16x8*)(pk + (size_t)gid * 8) = h;
}

// ---------------------------------------------------------------------------
// fused:
//  Phase A: register rolling-window segment-causal conv, 32 rows x 512 ch
//           -> LDS A-tile (bf16, chunk-XOR swizzle). 256 thr = 128 quads x
//           2 strips of 16 rows. No LDS reads.
//  ONE __syncthreads().
//  Phase B: barrier-free GEMM. 4 waves x (32 rows x 128 cols), acc[2][8];
//           B-frags L2->VGPR from packed layout (coalesced 16B/lane).
// Grid: 1024 blocks x 256 thr; As=32KB -> 4 blocks/CU (4 generations,
// naturally de-phased: gen g+1 conv overlaps gen g gemm/write).
// ---------------------------------------------------------------------------
__global__ __launch_bounds__(256, 4) void fused_kernel(
    const float* __restrict__ x, const int* __restrict__ segb,
    const float* __restrict__ w_dw, const bf16* __restrict__ pk,
    const float* __restrict__ bias2, float* __restrict__ out) {
  __shared__ __align__(16) bf16 As[BM * C_];  // 32 KB

  const int t = threadIdx.x;
  const int lane = t & 63;
  const int b = blockIdx.x >> 7;           // 128 m-tiles per batch row
  const int l0 = (blockIdx.x & 127) << 5;  // tile * 32

  // ================= Phase A: conv -> As =================
  const int q = t & 127;         // channel quad (4 ch)
  const int r0 = (t >> 7) << 4;  // row strip 0/16

  float4 raw[5];
#pragma unroll
  for (int i = 0; i < 5; ++i)
    raw[i] = *(const float4*)(w_dw + q * 20 + i * 4);
  f32x4 wt[5];
#pragma unroll
  for (int m = 0; m < 5; ++m)
#pragma unroll
    for (int i = 0; i < 4; ++i) {
      const int f = i * 5 + m;
      wt[m][i] = ((const float*)&raw[f >> 2])[f & 3];
    }

  const int* sb = segb + b * NS * 2;
  int stv[NS];
#pragma unroll
  for (int s = 0; s < NS; ++s) stv[s] = sb[2 * s];
  auto nxt = [&](int l) {
    int nn = INT_MAX;
#pragma unroll
    for (int s = 0; s < NS; ++s)
      nn = (stv[s] > l && stv[s] < nn) ? stv[s] : nn;
    return nn;
  };
  int ns = nxt(l0 + r0 - 4);

  const float* gxb = x + (size_t)(b * L_ + l0 + r0) * C_ + q * 4;

  const f32x4 z4 = (f32x4){0.f, 0.f, 0.f, 0.f};
  f32x4 w0 = z4, w1 = z4, w2 = z4, w3 = z4;

#pragma unroll
  for (int i = 0; i < 4; ++i) {
    const int l = l0 + r0 - 4 + i;
    f32x4 nv = z4;
    if (l >= 0) nv = *(const f32x4*)(gxb + (ptrdiff_t)(i - 4) * C_);
    if (l == ns) { w0 = z4; w1 = z4; w2 = z4; w3 = z4; ns = nxt(l); }
    w0 = w1; w1 = w2; w2 = w3; w3 = nv;
  }

  auto dorow = [&](int l, f32x4& A, f32x4& B4, f32x4& Cc, f32x4& D,
                   const f32x4& E, int rloc) {
    if (l == ns) { A = z4; B4 = z4; Cc = z4; D = z4; ns = nxt(l); }
    f32x4 r;
#pragma unroll
    for (int i = 0; i < 4; ++i) {
      float a = A[i] * wt[0][i];
      a = fmaf(B4[i], wt[1][i], a);
      a = fmaf(Cc[i], wt[2][i], a);
      a = fmaf(D[i], wt[3][i], a);
      a = fmaf(E[i], wt[4][i], a);
      r[i] = a;
    }
    bf16x4 h;
#pragma unroll
    for (int i = 0; i < 4; ++i) h[i] = (bf16)r[i];
    const int u = q ^ ((rloc & 7) << 1);  // quad-unit XOR swizzle
    *(bf16x4*)&As[rloc * 512 + u * 4] = h;
  };

#pragma unroll
  for (int g = 0; g < 4; ++g) {
    const int lb = l0 + r0 + g * 4;
    f32x4 n0 = *(const f32x4*)(gxb + (ptrdiff_t)(g * 4 + 0) * C_);
    f32x4 n1 = *(const f32x4*)(gxb + (ptrdiff_t)(g * 4 + 1) * C_);
    f32x4 n2 = *(const f32x4*)(gxb + (ptrdiff_t)(g * 4 + 2) * C_);
    f32x4 n3 = *(const f32x4*)(gxb + (ptrdiff_t)(g * 4 + 3) * C_);
    dorow(lb + 0, w0, w1, w2, w3, n0, r0 + g * 4 + 0);
    dorow(lb + 1, w1, w2, w3, n0, n1, r0 + g * 4 + 1);
    dorow(lb + 2, w2, w3, n0, n1, n2, r0 + g * 4 + 2);
    dorow(lb + 3, w3, n0, n1, n2, n3, r0 + g * 4 + 3);
    w0 = n0; w1 = n1; w2 = n2; w3 = n3;
  }

  __syncthreads();  // the ONLY barrier: As now read-only

  // ================= Phase B: barrier-free GEMM (4 waves x 128 cols) ======
  const int wn = t >> 6;     // 0..3
  const int cg = lane >> 4;  // k-chunk group
  const int rx = lane & 7;

  const int aRow0 = (lane & 15) * 512;
  const int aRow1 = (16 + (lane & 15)) * 512;
  const bf16* pb = pk + (size_t)wn * 4096 + lane * 8;  // groups 2wn,2wn+1

  f32x4 acc[2][8];
#pragma unroll
  for (int i = 0; i < 2; ++i)
#pragma unroll
    for (int j = 0; j < 8; ++j) acc[i][j] = z4;

#pragma unroll 1
  for (int kk = 0; kk < 16; ++kk) {
    const bf16* pws = pb + kk * 16384;
    bf16x8 bb[8];
#pragma unroll
    for (int nf = 0; nf < 8; ++nf)
      bb[nf] = *(const bf16x8*)(pws + nf * 512);
    const int ao = ((kk * 4 + cg) ^ rx) << 3;
    bf16x8 a0 = *(const bf16x8*)&As[aRow0 + ao];
    bf16x8 a1 = *(const bf16x8*)&As[aRow1 + ao];
    __builtin_amdgcn_s_setprio(1);
#pragma unroll
    for (int nf = 0; nf < 8; ++nf) {
      acc[0][nf] = __builtin_amdgcn_mfma_f32_16x16x32_bf16(a0, bb[nf],
                                                           acc[0][nf], 0, 0, 0);
      acc[1][nf] = __builtin_amdgcn_mfma_f32_16x16x32_bf16(a1, bb[nf],
                                                           acc[1][nf], 0, 0, 0);
    }
    __builtin_amdgcn_s_setprio(0);
  }

  // ---- epilogue: fp32 + bias2 (b_pw + W.b_dw folded, fp32-exact)
  const int col0 = wn * 128 + (lane & 15);
  float bia[8];
#pragma unroll
  for (int nf = 0; nf < 8; ++nf) bia[nf] = bias2[col0 + nf * 16];
  const int rb0 = l0 + (cg << 2);
#pragma unroll
  for (int mf = 0; mf < 2; ++mf) {
#pragma unroll
    for (int i = 0; i < 4; ++i) {
      const int row = rb0 + mf * 16 + i;
      float* o = out + (size_t)(b * L_ + row) * C_ + col0;
#pragma unroll
      for (int nf = 0; nf < 8; ++nf) o[nf * 16] = acc[mf][nf][i] + bia[nf];
    }
  }
}

extern "C" void kernel_launch(void* const* d_in, const int* in_sizes, int n_in,
                              void* d_out, int out_size, void* d_ws,
                              size_t ws_size, hipStream_t stream) {
  const float* x = (const float*)d_in[0];
  const int* segb = (const int*)d_in[1];      // [B][S][2] int32
  const float* w_dw = (const float*)d_in[2];  // [C][K]
  const float* b_dw = (const float*)d_in[3];  // [C]
  const float* w_pw = (const float*)d_in[4];  // [C_out][C_in]
  const float* b_pw = (const float*)d_in[5];  // [C]
  float* out = (float*)d_out;

  float* bias2 = (float*)d_ws;             // 4 KB
  bf16* pk = (bf16*)((char*)d_ws + 4096);  // 512 KB packed B

  bias_kernel<<<C_, 256, 0, stream>>>(w_pw, b_dw, b_pw, bias2);
  pack_kernel<<<128, 256, 0, stream>>>(w_pw, pk);
  fused_kernel<<<NB * L_ / BM, 256, 0, stream>>>(x, segb, w_dw, pk, bias2,
                                                 out);
}

// Round 13
// 46.405 us; speedup vs baseline: 1.0097x; 1.0097x over previous
//
#include <hip/hip_runtime.h>
#include <hip/hip_bf16.h>
#include <climits>

typedef __bf16 bf16;
typedef __bf16 bf16x4 __attribute__((ext_vector_type(4)));
typedef __bf16 bf16x8 __attribute__((ext_vector_type(8)));
typedef float f32x4 __attribute__((ext_vector_type(4)));

#define NB 8
#define L_ 4096
#define C_ 512
#define KW 5
#define NS 8
#define BM 32
// pad As to 56 KB so exactly 2 blocks/CU fit (capacity 512 < grid 1024
// => 512 retirement-staggered queued blocks)
#define AS_ELEMS (BM * C_ + 12288)

// ---------------------------------------------------------------------------
// bias2[n] = b_pw[n] + sum_c b_dw[c]*w_pw[n][c]   (fp32-exact)
// ---------------------------------------------------------------------------
__global__ __launch_bounds__(256) void bias_kernel(
    const float* __restrict__ w_pw, const float* __restrict__ b_dw,
    const float* __restrict__ b_pw, float* __restrict__ bias2) {
  const int n = blockIdx.x;
  const int t = threadIdx.x;
  float2 v = *(const float2*)(w_pw + n * C_ + 2 * t);
  float2 bb = *(const float2*)(b_dw + 2 * t);
  float s = v.x * bb.x + v.y * bb.y;
#pragma unroll
  for (int off = 32; off; off >>= 1) s += __shfl_down(s, off, 64);
  __shared__ float part[4];
  if ((t & 63) == 0) part[t >> 6] = s;
  __syncthreads();
  if (t == 0) bias2[n] = b_pw[n] + part[0] + part[1] + part[2] + part[3];
}

// ---------------------------------------------------------------------------
// pack: w_pw fp32 -> bf16 in MFMA B-fragment order for the 8-wave layout.
// gid = ((kk*8 + wn)*4 + nf)*64 + lane holds 8 bf16 (16B):
//   col n = wn*64 + nf*16 + (lane&15), ch c = kk*32 + (lane>>4)*8 .. +8
// ---------------------------------------------------------------------------
__global__ __launch_bounds__(256) void pack_kernel(const float* __restrict__ w_pw,
                                                   bf16* __restrict__ pk) {
  const int gid = blockIdx.x * 256 + threadIdx.x;  // 0..32767
  const int lane = gid & 63;
  const int nf = (gid >> 6) & 3;
  const int wnn = (gid >> 8) & 7;
  const int kk = gid >> 11;
  const int n = wnn * 64 + nf * 16 + (lane & 15);
  const int c = kk * 32 + (lane >> 4) * 8;
  const float* s = w_pw + n * C_ + c;
  float4 a = *(const float4*)s;
  float4 b4 = *(const float4*)(s + 4);
  bf16x8 h;
  h[0] = (bf16)a.x; h[1] = (bf16)a.y; h[2] = (bf16)a.z; h[3] = (bf16)a.w;
  h[4] = (bf16)b4.x; h[5] = (bf16)b4.y; h[6] = (bf16)b4.z; h[7] = (bf16)b4.w;
  *(bf16x8*)(pk + (size_t)gid * 8) = h;
}

// ---------------------------------------------------------------------------
// fused:
//  Phase A: register rolling-window segment-causal conv, 32 rows x 512 ch
//           -> LDS A-tile (bf16, chunk-XOR swizzle). 512 thr = 128 quads x
//           4 strips of 8 rows. No LDS reads.
//  ONE __syncthreads().
//  Phase B: barrier-free GEMM. 8 waves x (32 rows x 64 cols), acc[2][4];
//           B-frags L2->VGPR from packed layout, ping-pong prefetched.
// Grid: 1024 blocks x 512 thr; As padded to 56 KB -> 2 blocks/CU resident,
// 512 blocks queued => retirement-staggered generations: queued conv (HBM
// reads) overlaps resident gemm (L2/MFMA) and epilogue write drains.
// ---------------------------------------------------------------------------
__global__ __launch_bounds__(512, 4) void fused_kernel(
    const float* __restrict__ x, const int* __restrict__ segb,
    const float* __restrict__ w_dw, const bf16* __restrict__ pk,
    const float* __restrict__ bias2, float* __restrict__ out) {
  __shared__ __align__(16) bf16 As[AS_ELEMS];  // 56 KB (32 KB used)

  const int t = threadIdx.x;
  const int lane = t & 63;
  const int b = blockIdx.x >> 7;           // 128 m-tiles per batch row
  const int l0 = (blockIdx.x & 127) << 5;  // tile * 32

  // ================= Phase A: conv -> As =================
  const int q = t & 127;         // channel quad (4 ch)
  const int r0 = (t >> 7) << 3;  // row strip 0/8/16/24

  float4 raw[5];
#pragma unroll
  for (int i = 0; i < 5; ++i)
    raw[i] = *(const float4*)(w_dw + q * 20 + i * 4);
  f32x4 wt[5];
#pragma unroll
  for (int m = 0; m < 5; ++m)
#pragma unroll
    for (int i = 0; i < 4; ++i) {
      const int f = i * 5 + m;
      wt[m][i] = ((const float*)&raw[f >> 2])[f & 3];
    }

  const int* sb = segb + b * NS * 2;
  int stv[NS];
#pragma unroll
  for (int s = 0; s < NS; ++s) stv[s] = sb[2 * s];
  auto nxt = [&](int l) {
    int nn = INT_MAX;
#pragma unroll
    for (int s = 0; s < NS; ++s)
      nn = (stv[s] > l && stv[s] < nn) ? stv[s] : nn;
    return nn;
  };
  int ns = nxt(l0 + r0 - 4);

  const float* gxb = x + (size_t)(b * L_ + l0 + r0) * C_ + q * 4;

  const f32x4 z4 = (f32x4){0.f, 0.f, 0.f, 0.f};
  f32x4 w0 = z4, w1 = z4, w2 = z4, w3 = z4;

#pragma unroll
  for (int i = 0; i < 4; ++i) {
    const int l = l0 + r0 - 4 + i;
    f32x4 nv = z4;
    if (l >= 0) nv = *(const f32x4*)(gxb + (ptrdiff_t)(i - 4) * C_);
    if (l == ns) { w0 = z4; w1 = z4; w2 = z4; w3 = z4; ns = nxt(l); }
    w0 = w1; w1 = w2; w2 = w3; w3 = nv;
  }

  auto dorow = [&](int l, f32x4& A, f32x4& B4, f32x4& Cc, f32x4& D,
                   const f32x4& E, int rloc) {
    if (l == ns) { A = z4; B4 = z4; Cc = z4; D = z4; ns = nxt(l); }
    f32x4 r;
#pragma unroll
    for (int i = 0; i < 4; ++i) {
      float a = A[i] * wt[0][i];
      a = fmaf(B4[i], wt[1][i], a);
      a = fmaf(Cc[i], wt[2][i], a);
      a = fmaf(D[i], wt[3][i], a);
      a = fmaf(E[i], wt[4][i], a);
      r[i] = a;
    }
    bf16x4 h;
#pragma unroll
    for (int i = 0; i < 4; ++i) h[i] = (bf16)r[i];
    const int u = q ^ ((rloc & 7) << 1);  // quad-unit XOR swizzle
    *(bf16x4*)&As[rloc * 512 + u * 4] = h;
  };

#pragma unroll
  for (int g = 0; g < 2; ++g) {
    const int lb = l0 + r0 + g * 4;
    f32x4 n0 = *(const f32x4*)(gxb + (ptrdiff_t)(g * 4 + 0) * C_);
    f32x4 n1 = *(const f32x4*)(gxb + (ptrdiff_t)(g * 4 + 1) * C_);
    f32x4 n2 = *(const f32x4*)(gxb + (ptrdiff_t)(g * 4 + 2) * C_);
    f32x4 n3 = *(const f32x4*)(gxb + (ptrdiff_t)(g * 4 + 3) * C_);
    dorow(lb + 0, w0, w1, w2, w3, n0, r0 + g * 4 + 0);
    dorow(lb + 1, w1, w2, w3, n0, n1, r0 + g * 4 + 1);
    dorow(lb + 2, w2, w3, n0, n1, n2, r0 + g * 4 + 2);
    dorow(lb + 3, w3, n0, n1, n2, n3, r0 + g * 4 + 3);
    w0 = n0; w1 = n1; w2 = n2; w3 = n3;
  }

  __syncthreads();  // the ONLY barrier: As now read-only

  // ================= Phase B: barrier-free GEMM (8 waves x 64 cols) =======
  const int wn = t >> 6;     // 0..7
  const int cg = lane >> 4;  // k-chunk group
  const int rx = lane & 7;

  const int aRow0 = (lane & 15) * 512;
  const int aRow1 = (16 + (lane & 15)) * 512;
  const bf16* pb = pk + (size_t)wn * 2048 + lane * 8;

  f32x4 acc[2][4];
#pragma unroll
  for (int i = 0; i < 2; ++i)
#pragma unroll
    for (int j = 0; j < 4; ++j) acc[i][j] = z4;

  bf16x8 bbA[4], bbB[4];
#pragma unroll
  for (int nf = 0; nf < 4; ++nf)
    bbA[nf] = *(const bf16x8*)(pb + nf * 512);  // bb(0)

#pragma unroll 1
  for (int kk = 0; kk < 16; kk += 2) {
    // even step: prefetch bb(kk+1), compute with bbA
#pragma unroll
    for (int nf = 0; nf < 4; ++nf)
      bbB[nf] = *(const bf16x8*)(pb + (kk + 1) * 16384 + nf * 512);
    const int ao = ((kk * 4 + cg) ^ rx) << 3;
    bf16x8 a0 = *(const bf16x8*)&As[aRow0 + ao];
    bf16x8 a1 = *(const bf16x8*)&As[aRow1 + ao];
    __builtin_amdgcn_s_setprio(1);
#pragma unroll
    for (int nf = 0; nf < 4; ++nf) {
      acc[0][nf] = __builtin_amdgcn_mfma_f32_16x16x32_bf16(a0, bbA[nf],
                                                           acc[0][nf], 0, 0, 0);
      acc[1][nf] = __builtin_amdgcn_mfma_f32_16x16x32_bf16(a1, bbA[nf],
                                                           acc[1][nf], 0, 0, 0);
    }
    __builtin_amdgcn_s_setprio(0);

    // odd step: prefetch bb(kk+2), compute with bbB
    if (kk + 2 < 16) {
#pragma unroll
      for (int nf = 0; nf < 4; ++nf)
        bbA[nf] = *(const bf16x8*)(pb + (kk + 2) * 16384 + nf * 512);
    }
    const int ao2 = (((kk + 1) * 4 + cg) ^ rx) << 3;
    bf16x8 a2 = *(const bf16x8*)&As[aRow0 + ao2];
    bf16x8 a3 = *(const bf16x8*)&As[aRow1 + ao2];
    __builtin_amdgcn_s_setprio(1);
#pragma unroll
    for (int nf = 0; nf < 4; ++nf) {
      acc[0][nf] = __builtin_amdgcn_mfma_f32_16x16x32_bf16(a2, bbB[nf],
                                                           acc[0][nf], 0, 0, 0);
      acc[1][nf] = __builtin_amdgcn_mfma_f32_16x16x32_bf16(a3, bbB[nf],
                                                           acc[1][nf], 0, 0, 0);
    }
    __builtin_amdgcn_s_setprio(0);
  }

  // ---- epilogue: fp32 + bias2 (b_pw + W.b_dw folded, fp32-exact)
  const int col0 = wn * 64 + (lane & 15);
  float bia[4];
#pragma unroll
  for (int nf = 0; nf < 4; ++nf) bia[nf] = bias2[col0 + nf * 16];
  const int rb0 = l0 + (cg << 2);
#pragma unroll
  for (int mf = 0; mf < 2; ++mf) {
#pragma unroll
    for (int i = 0; i < 4; ++i) {
      const int row = rb0 + mf * 16 + i;
      float* o = out + (size_t)(b * L_ + row) * C_ + col0;
#pragma unroll
      for (int nf = 0; nf < 4; ++nf) o[nf * 16] = acc[mf][nf][i] + bia[nf];
    }
  }
}

extern "C" void kernel_launch(void* const* d_in, const int* in_sizes, int n_in,
                              void* d_out, int out_size, void* d_ws,
                              size_t ws_size, hipStream_t stream) {
  const float* x = (const float*)d_in[0];
  const int* segb = (const int*)d_in[1];      // [B][S][2] int32
  const float* w_dw = (const float*)d_in[2];  // [C][K]
  const float* b_dw = (const float*)d_in[3];  // [C]
  const float* w_pw = (const float*)d_in[4];  // [C_out][C_in]
  const float* b_pw = (const float*)d_in[5];  // [C]
  float* out = (float*)d_out;

  float* bias2 = (float*)d_ws;             // 4 KB
  bf16* pk = (bf16*)((char*)d_ws + 4096);  // 512 KB packed B

  bias_kernel<<<C_, 256, 0, stream>>>(w_pw, b_dw, b_pw, bias2);
  pack_kernel<<<128, 256, 0, stream>>>(w_pw, pk);
  fused_kernel<<<NB * L_ / BM, 512, 0, stream>>>(x, segb, w_dw, pk, bias2,
                                                 out);
}

// Round 14
// 39.934 us; speedup vs baseline: 1.1733x; 1.1620x over previous
//
#include <hip/hip_runtime.h>
#include <hip/hip_bf16.h>
#include <climits>

typedef __bf16 bf16;
typedef __bf16 bf16x4 __attribute__((ext_vector_type(4)));
typedef __bf16 bf16x8 __attribute__((ext_vector_type(8)));
typedef float f32x4 __attribute__((ext_vector_type(4)));

#define NB 8
#define L_ 4096
#define C_ 512
#define KW 5
#define NS 8
#define BM 64

// ---------------------------------------------------------------------------
// prep (merged): blocks 0..127 pack w_pw -> bf16 MFMA B-frag order;
//                blocks 128..639 compute bias2[n] = b_pw[n] + w_pw[n,:].b_dw
// pack: gid = ((kk*8 + wn)*4 + nf)*64 + lane holds 8 bf16 (16B):
//   col n = wn*64 + nf*16 + (lane&15), ch c = kk*32 + (lane>>4)*8 .. +8
// ---------------------------------------------------------------------------
__global__ __launch_bounds__(256) void prep_kernel(
    const float* __restrict__ w_pw, const float* __restrict__ b_dw,
    const float* __restrict__ b_pw, bf16* __restrict__ pk,
    float* __restrict__ bias2) {
  const int t = threadIdx.x;
  if (blockIdx.x < 128) {
    const int gid = blockIdx.x * 256 + t;  // 0..32767
    const int lane = gid & 63;
    const int nf = (gid >> 6) & 3;
    const int wnn = (gid >> 8) & 7;
    const int kk = gid >> 11;
    const int n = wnn * 64 + nf * 16 + (lane & 15);
    const int c = kk * 32 + (lane >> 4) * 8;
    const float* s = w_pw + n * C_ + c;
    float4 a = *(const float4*)s;
    float4 b4 = *(const float4*)(s + 4);
    bf16x8 h;
    h[0] = (bf16)a.x; h[1] = (bf16)a.y; h[2] = (bf16)a.z; h[3] = (bf16)a.w;
    h[4] = (bf16)b4.x; h[5] = (bf16)b4.y; h[6] = (bf16)b4.z; h[7] = (bf16)b4.w;
    *(bf16x8*)(pk + (size_t)gid * 8) = h;
  } else {
    const int n = blockIdx.x - 128;  // 0..511
    float2 v = *(const float2*)(w_pw + n * C_ + 2 * t);
    float2 bb = *(const float2*)(b_dw + 2 * t);
    float s = v.x * bb.x + v.y * bb.y;
#pragma unroll
    for (int off = 32; off; off >>= 1) s += __shfl_down(s, off, 64);
    __shared__ float part[4];
    if ((t & 63) == 0) part[t >> 6] = s;
    __syncthreads();
    if (t == 0) bias2[n] = b_pw[n] + part[0] + part[1] + part[2] + part[3];
  }
}

// ---------------------------------------------------------------------------
// fused (R9 structure, proven 42.4 µs):
//  Phase A: register rolling-window segment-causal conv, 64 rows x 512 ch
//           -> LDS A-tile (bf16, chunk-XOR swizzle). 512 thr = 128 quads x
//           4 strips of 16 rows. Row-group loads 3-deep (p0,p1,p2) to cover
//           L3 latency. No LDS reads.
//  ONE __syncthreads().
//  Phase B: barrier-free GEMM, 1Mx8N: each of 8 waves owns 64 rows x 64
//           cols (acc[4][4]); B-frags bb[4] loaded L2->VGPR from packed pk
//           (coalesced 16B/lane) and reused across 4 A-frags.
// Grid: 512 blocks x 512 thr; As=64KB -> 2 blocks/CU, 16 waves/CU.
// ---------------------------------------------------------------------------
__global__ __launch_bounds__(512, 4) void fused_kernel(
    const float* __restrict__ x, const int* __restrict__ segb,
    const float* __restrict__ w_dw, const bf16* __restrict__ pk,
    const float* __restrict__ bias2, float* __restrict__ out) {
  __shared__ __align__(16) bf16 As[BM * C_];  // 64 KB

  const int t = threadIdx.x;
  const int lane = t & 63;
  const int b = blockIdx.x >> 6;          // 64 m-tiles per batch row
  const int l0 = (blockIdx.x & 63) << 6;  // tile * 64

  // ================= Phase A: conv -> As =================
  const int q = t & 127;         // channel quad (4 ch)
  const int r0 = (t >> 7) << 4;  // row strip 0/16/32/48

  float4 raw[5];
#pragma unroll
  for (int i = 0; i < 5; ++i)
    raw[i] = *(const float4*)(w_dw + q * 20 + i * 4);
  f32x4 wt[5];
#pragma unroll
  for (int m = 0; m < 5; ++m)
#pragma unroll
    for (int i = 0; i < 4; ++i) {
      const int f = i * 5 + m;
      wt[m][i] = ((const float*)&raw[f >> 2])[f & 3];
    }

  const int* sb = segb + b * NS * 2;
  int stv[NS];
#pragma unroll
  for (int s = 0; s < NS; ++s) stv[s] = sb[2 * s];
  auto nxt = [&](int l) {
    int nn = INT_MAX;
#pragma unroll
    for (int s = 0; s < NS; ++s)
      nn = (stv[s] > l && stv[s] < nn) ? stv[s] : nn;
    return nn;
  };
  int ns = nxt(l0 + r0 - 4);

  const float* gxb = x + (size_t)(b * L_ + l0 + r0) * C_ + q * 4;

  const f32x4 z4 = (f32x4){0.f, 0.f, 0.f, 0.f};
  f32x4 w0 = z4, w1 = z4, w2 = z4, w3 = z4;

  // 3-deep row-group prefetch buffers
  f32x4 p0[4], p1[4], p2[4];
  auto ldg = [&](int g, f32x4 (&p)[4]) {
#pragma unroll
    for (int j = 0; j < 4; ++j)
      p[j] = *(const f32x4*)(gxb + (ptrdiff_t)(g * 4 + j) * C_);
  };
  ldg(0, p0);
  ldg(1, p1);
  ldg(2, p2);

  // warmup rows l0+r0-4 .. l0+r0-1 (zero left edge / segment resets)
#pragma unroll
  for (int i = 0; i < 4; ++i) {
    const int l = l0 + r0 - 4 + i;
    f32x4 nv = z4;
    if (l >= 0) nv = *(const f32x4*)(gxb + (ptrdiff_t)(i - 4) * C_);
    if (l == ns) { w0 = z4; w1 = z4; w2 = z4; w3 = z4; ns = nxt(l); }
    w0 = w1; w1 = w2; w2 = w3; w3 = nv;
  }

  auto dorow = [&](int l, f32x4& A, f32x4& B4, f32x4& Cc, f32x4& D,
                   const f32x4& E, int rloc) {
    if (l == ns) { A = z4; B4 = z4; Cc = z4; D = z4; ns = nxt(l); }
    f32x4 r;
#pragma unroll
    for (int i = 0; i < 4; ++i) {
      float a = A[i] * wt[0][i];
      a = fmaf(B4[i], wt[1][i], a);
      a = fmaf(Cc[i], wt[2][i], a);
      a = fmaf(D[i], wt[3][i], a);
      a = fmaf(E[i], wt[4][i], a);
      r[i] = a;
    }
    bf16x4 h;
#pragma unroll
    for (int i = 0; i < 4; ++i) h[i] = (bf16)r[i];
    const int u = q ^ ((rloc & 7) << 1);  // quad-unit XOR swizzle
    *(bf16x4*)&As[rloc * 512 + u * 4] = h;
  };

  auto compute = [&](int g, f32x4 (&p)[4]) {
    const int lb = l0 + r0 + g * 4;
    dorow(lb + 0, w0, w1, w2, w3, p[0], r0 + g * 4 + 0);
    dorow(lb + 1, w1, w2, w3, p[0], p[1], r0 + g * 4 + 1);
    dorow(lb + 2, w2, w3, p[0], p[1], p[2], r0 + g * 4 + 2);
    dorow(lb + 3, w3, p[0], p[1], p[2], p[3], r0 + g * 4 + 3);
    w0 = p[0]; w1 = p[1]; w2 = p[2]; w3 = p[3];
  };

  compute(0, p0);
  ldg(3, p0);  // reuse p0 for the last group
  compute(1, p1);
  compute(2, p2);
  compute(3, p0);

  __syncthreads();  // the ONLY barrier: As now read-only

  // ================= Phase B: barrier-free GEMM (1M x 8N) =================
  const int wn = t >> 6;     // 0..7
  const int cg = lane >> 4;  // k-chunk group
  const int rx = lane & 7;

  int aRow[4];
#pragma unroll
  for (int mf = 0; mf < 4; ++mf) aRow[mf] = (mf * 16 + (lane & 15)) * 512;
  const bf16* pw = pk + (size_t)wn * 2048 + lane * 8;  // packed-B wave base

  f32x4 acc[4][4];
#pragma unroll
  for (int i = 0; i < 4; ++i)
#pragma unroll
    for (int j = 0; j < 4; ++j) acc[i][j] = z4;

#pragma unroll 1
  for (int kk = 0; kk < 16; ++kk) {
    const bf16* pws = pw + kk * 16384;
    bf16x8 bb[4];
#pragma unroll
    for (int nf = 0; nf < 4; ++nf)
      bb[nf] = *(const bf16x8*)(pws + nf * 512);
    const int ao = ((kk * 4 + cg) ^ rx) << 3;
    bf16x8 af[4];
#pragma unroll
    for (int mf = 0; mf < 4; ++mf)
      af[mf] = *(const bf16x8*)&As[aRow[mf] + ao];
    __builtin_amdgcn_s_setprio(1);
#pragma unroll
    for (int nf = 0; nf < 4; ++nf)
#pragma unroll
      for (int mf = 0; mf < 4; ++mf)
        acc[mf][nf] = __builtin_amdgcn_mfma_f32_16x16x32_bf16(
            af[mf], bb[nf], acc[mf][nf], 0, 0, 0);
    __builtin_amdgcn_s_setprio(0);
  }

  // ---- epilogue: fp32 + bias2 (b_pw + W.b_dw folded, fp32-exact)
  const int col0 = wn * 64 + (lane & 15);
  float bia[4];
#pragma unroll
  for (int nf = 0; nf < 4; ++nf) bia[nf] = bias2[col0 + nf * 16];
  const int rb0 = l0 + (cg << 2);
#pragma unroll
  for (int mf = 0; mf < 4; ++mf) {
#pragma unroll
    for (int i = 0; i < 4; ++i) {
      const int row = rb0 + mf * 16 + i;
      float* o = out + (size_t)(b * L_ + row) * C_ + col0;
#pragma unroll
      for (int nf = 0; nf < 4; ++nf) o[nf * 16] = acc[mf][nf][i] + bia[nf];
    }
  }
}

extern "C" void kernel_launch(void* const* d_in, const int* in_sizes, int n_in,
                              void* d_out, int out_size, void* d_ws,
                              size_t ws_size, hipStream_t stream) {
  const float* x = (const float*)d_in[0];
  const int* segb = (const int*)d_in[1];      // [B][S][2] int32
  const float* w_dw = (const float*)d_in[2];  // [C][K]
  const float* b_dw = (const float*)d_in[3];  // [C]
  const float* w_pw = (const float*)d_in[4];  // [C_out][C_in]
  const float* b_pw = (const float*)d_in[5];  // [C]
  float* out = (float*)d_out;

  float* bias2 = (float*)d_ws;             // 4 KB
  bf16* pk = (bf16*)((char*)d_ws + 4096);  // 512 KB packed B

  prep_kernel<<<640, 256, 0, stream>>>(w_pw, b_dw, b_pw, pk, bias2);
  fused_kernel<<<NB * L_ / BM, 512, 0, stream>>>(x, segb, w_dw, pk, bias2,
                                                 out);
}